// Round 1
// baseline (132.648 us; speedup 1.0000x reference)
//
#include <hip/hip_runtime.h>

// RoleScorer: scores[b,s,t,o] = relu(a[b,s]@W1a + b[b,t]@W1b + b1) @ W2 + b2
// Fused biaffine form: never materialize the (4,128,128,768) h tensor.
//
// Kernel 1 (proj): hA = a@W1[:768] + b1   (bias folded here, once)
//                  hB = b@W1[768:]        (no bias)
//   f32 tiled GEMM, 64x64 tile, 256 thr, 4x4 micro, K-tile 16.
//   M=512 (B*S flattened), N=768, K=768. grid (12,8,2) = 192 blocks.
// Kernel 2 (pair): per (batch, 16s x 16t) tile, chunk H by 128 through LDS,
//   each thread owns one (s,t) pair, 2 f32 accumulators (O=2).
//   grid (8,8,4) = 256 blocks.

#define MT 64
#define NT 64
#define KT 16

__global__ __launch_bounds__(256) void proj_kernel(
    const float* __restrict__ a,    // (512, 768)
    const float* __restrict__ b,    // (512, 768)
    const float* __restrict__ W1,   // (1536, 768) row-major
    const float* __restrict__ b1,   // (768)
    float* __restrict__ hA,         // (512, 768)
    float* __restrict__ hB)         // (512, 768)
{
    const int M = 512, N = 768, K = 768;
    (void)M;
    const int which = blockIdx.z;
    const float* __restrict__ A   = (which == 0) ? a : b;
    const float* __restrict__ W   = W1 + (which == 0 ? 0 : K * N);
    float* __restrict__ Out       = (which == 0) ? hA : hB;

    const int n0 = blockIdx.x * NT;
    const int m0 = blockIdx.y * MT;
    const int tid = threadIdx.x;
    const int tx = tid & 15;   // n-direction
    const int ty = tid >> 4;   // m-direction

    // +4 pad: keeps float4 alignment (68*4B = 272B, 16B-multiple) and breaks
    // power-of-2 bank stride on the transposed A store.
    __shared__ float As[KT][MT + 4];   // [k][m]
    __shared__ float Ws[KT][NT + 4];   // [k][n]

    float acc[4][4];
#pragma unroll
    for (int i = 0; i < 4; i++)
#pragma unroll
        for (int j = 0; j < 4; j++) acc[i][j] = 0.f;

    // A staging: 64 rows x 16 k = 256 float4; thread -> (row = tid/4, kchunk = (tid&3)*4)
    const int arow = tid >> 2;
    const int akc  = (tid & 3) * 4;
    // W staging: 16 k x 64 n = 256 float4; thread -> (k = tid/16, nchunk = (tid&15)*4)
    const int wk  = tid >> 4;
    const int wnc = (tid & 15) * 4;

    const float* __restrict__ Arow_ptr = &A[(m0 + arow) * K + akc];
    const float* __restrict__ Wrow_ptr = &W[wk * N + n0 + wnc];

    for (int kt = 0; kt < K; kt += KT) {
        const float4 av = *(const float4*)(Arow_ptr + kt);
        const float4 wv = *(const float4*)(Wrow_ptr + (size_t)kt * N);

        __syncthreads();   // previous tile fully consumed
        As[akc + 0][arow] = av.x;
        As[akc + 1][arow] = av.y;
        As[akc + 2][arow] = av.z;
        As[akc + 3][arow] = av.w;
        *(float4*)&Ws[wk][wnc] = wv;
        __syncthreads();

#pragma unroll
        for (int kk = 0; kk < KT; kk++) {
            const float4 af = *(const float4*)&As[kk][ty * 4];
            const float4 wf = *(const float4*)&Ws[kk][tx * 4];
            const float am[4] = {af.x, af.y, af.z, af.w};
            const float wn[4] = {wf.x, wf.y, wf.z, wf.w};
#pragma unroll
            for (int i = 0; i < 4; i++)
#pragma unroll
                for (int j = 0; j < 4; j++)
                    acc[i][j] = fmaf(am[i], wn[j], acc[i][j]);
        }
    }

    float4 bias = make_float4(0.f, 0.f, 0.f, 0.f);
    if (which == 0) bias = *(const float4*)&b1[n0 + tx * 4];

#pragma unroll
    for (int i = 0; i < 4; i++) {
        float4 o;
        o.x = acc[i][0] + bias.x;
        o.y = acc[i][1] + bias.y;
        o.z = acc[i][2] + bias.z;
        o.w = acc[i][3] + bias.w;
        *(float4*)&Out[(size_t)(m0 + ty * 4 + i) * N + n0 + tx * 4] = o;
    }
}

#define HC 128

__global__ __launch_bounds__(256) void pair_kernel(
    const float* __restrict__ hA,   // (4,128,768), bias already folded in
    const float* __restrict__ hB,   // (4,128,768)
    const float* __restrict__ W2,   // (768, 2)
    const float* __restrict__ b2,   // (2)
    float* __restrict__ out)        // (4,128,128,2)
{
    const int S = 128, H = 768;
    const int bb = blockIdx.z;
    const int s0 = blockIdx.y * 16;
    const int t0 = blockIdx.x * 16;
    const int tid = threadIdx.x;
    const int tl = tid & 15;   // t within tile
    const int sl = tid >> 4;   // s within tile

    // +4 pad: 132 stride -> bank shift of 4 per row (2-way max = free), 16B aligned
    __shared__ float hAs[16][HC + 4];
    __shared__ float hBs[16][HC + 4];

    const float* __restrict__ hAbase = hA + (size_t)(bb * S + s0) * H;
    const float* __restrict__ hBbase = hB + (size_t)(bb * S + t0) * H;

    float acc0 = 0.f, acc1 = 0.f;

    for (int hc = 0; hc < H; hc += HC) {
        __syncthreads();
        // stage 16 rows x 128 floats (= 512 float4) per array; 2 float4/thread
#pragma unroll
        for (int i = 0; i < 2; i++) {
            const int idx = tid + i * 256;
            const int row = idx >> 5;          // 32 float4 per row
            const int c4  = (idx & 31) * 4;
            const float4 va = *(const float4*)&hAbase[(size_t)row * H + hc + c4];
            const float4 vb = *(const float4*)&hBbase[(size_t)row * H + hc + c4];
            *(float4*)&hAs[row][c4] = va;
            *(float4*)&hBs[row][c4] = vb;
        }
        __syncthreads();

#pragma unroll
        for (int hh = 0; hh < HC; hh += 4) {
            const float4 va = *(const float4*)&hAs[sl][hh];
            const float4 vb = *(const float4*)&hBs[tl][hh];
            const float* __restrict__ w2p = &W2[(size_t)(hc + hh) * 2];
            float v;
            v = fmaxf(va.x + vb.x, 0.f);
            acc0 = fmaf(v, w2p[0], acc0); acc1 = fmaf(v, w2p[1], acc1);
            v = fmaxf(va.y + vb.y, 0.f);
            acc0 = fmaf(v, w2p[2], acc0); acc1 = fmaf(v, w2p[3], acc1);
            v = fmaxf(va.z + vb.z, 0.f);
            acc0 = fmaf(v, w2p[4], acc0); acc1 = fmaf(v, w2p[5], acc1);
            v = fmaxf(va.w + vb.w, 0.f);
            acc0 = fmaf(v, w2p[6], acc0); acc1 = fmaf(v, w2p[7], acc1);
        }
    }

    acc0 += b2[0];
    acc1 += b2[1];
    float2 r = make_float2(acc0, acc1);
    *(float2*)&out[((size_t)(bb * S + s0 + sl) * S + (t0 + tl)) * 2] = r;
}

extern "C" void kernel_launch(void* const* d_in, const int* in_sizes, int n_in,
                              void* d_out, int out_size, void* d_ws, size_t ws_size,
                              hipStream_t stream) {
    const float* a  = (const float*)d_in[0];
    const float* b  = (const float*)d_in[1];
    const float* W1 = (const float*)d_in[2];
    const float* b1 = (const float*)d_in[3];
    const float* W2 = (const float*)d_in[4];
    const float* b2 = (const float*)d_in[5];
    float* out = (float*)d_out;

    float* hA = (float*)d_ws;                 // 512*768 f32 = 1.5 MB
    float* hB = hA + 512 * 768;               // another 1.5 MB

    dim3 g1(768 / NT, 512 / MT, 2);           // (12, 8, 2) = 192 blocks
    proj_kernel<<<g1, 256, 0, stream>>>(a, b, W1, b1, hA, hB);

    dim3 g2(128 / 16, 128 / 16, 4);           // (8, 8, 4) = 256 blocks
    pair_kernel<<<g2, 256, 0, stream>>>(hA, hB, W2, b2, out);
}

// Round 2
// 98.548 us; speedup vs baseline: 1.3460x; 1.3460x over previous
//
#include <hip/hip_runtime.h>
#include <hip/hip_bf16.h>

// RoleScorer, fused biaffine:
//   hA = bf16(a @ W1[:768] + b1)   hB = bf16(b @ W1[768:])      (MFMA GEMM)
//   out[b,s,t,o] = sum_h relu(hA[s,h]+hB[t,h]) * W2[h,o] + b2   (VALU pair)
//
// K1 init_out : out[...] = b2 pattern (atomicAdd target)
// K2 gemm     : bf16 MFMA 16x16x32, 64x64 tile, 4 waves, K-step 32,
//               A staged f32->bf16, B (W1) transposed during staging
//               (wave w loads k-rows kt+8w..+8, coalesced across n).
// K3 pair     : 32x32 pair tile, 2x2 micro/thread, 4-way H split (192 h/blk),
//               bf16 LDS staging, W2 chunk in LDS, f32 atomicAdd epilogue.

typedef __attribute__((ext_vector_type(8))) short short8;
typedef __attribute__((ext_vector_type(4))) float floatx4;
typedef unsigned int uint;

__device__ __forceinline__ short f2bf(float f) {
    __hip_bfloat16 h = __float2bfloat16(f);
    short s; __builtin_memcpy(&s, &h, 2); return s;
}
__device__ __forceinline__ float bflo(uint u) {
    uint v = u << 16; float f; __builtin_memcpy(&f, &v, 4); return f;
}
__device__ __forceinline__ float bfhi(uint u) {
    uint v = u & 0xffff0000u; float f; __builtin_memcpy(&f, &v, 4); return f;
}

// ---------------- K1: out init = broadcast b2 ----------------
__global__ __launch_bounds__(256) void init_out_kernel(
    const float* __restrict__ b2, float* __restrict__ out)
{
    const float w0 = b2[0], w1 = b2[1];
    const float4 v = make_float4(w0, w1, w0, w1);
    const int base = blockIdx.x * 2048 + threadIdx.x * 8;
    *(float4*)&out[base]     = v;
    *(float4*)&out[base + 4] = v;
}

// ---------------- K2: bf16 MFMA GEMM ----------------
// grid (12, 8, 2): n0 = x*64, m0 = y*64, which = z (0: a/W1-top/+b1, 1: b/W1-bot)
__global__ __launch_bounds__(256) void gemm_kernel(
    const float* __restrict__ a, const float* __restrict__ bmat,
    const float* __restrict__ W1, const float* __restrict__ b1,
    ushort* __restrict__ Hbf)   // [2][512][768] bf16
{
    const int which = blockIdx.z;
    const int n0 = blockIdx.x * 64;
    const int m0 = blockIdx.y * 64;
    const int t  = threadIdx.x;

    // +8 bf16 pad: row stride 80 B (16B-aligned for b128)
    __shared__ ushort As[64][40];   // [m][k]
    __shared__ ushort Bs[64][40];   // [n][k]

    // A staging map: row = t>>2 (m), kc = (t&3)*8
    const int srow = t >> 2;
    const int skc  = (t & 3) * 8;
    const float* __restrict__ Asrc = which ? bmat : a;
    const float* __restrict__ aptr = Asrc + (size_t)(m0 + srow) * 768 + skc;

    // B staging map: ncol = t&63, k-group = (t>>6)*8 (wave w owns k-rows 8w..8w+8)
    const int ncolS = t & 63;
    const int kg0   = (t >> 6) * 8;
    const float* __restrict__ bptr = W1 + (size_t)(which * 768 + kg0) * 768 + n0 + ncolS;

    // prefetch kt = 0
    float4 af0 = *(const float4*)(aptr);
    float4 af1 = *(const float4*)(aptr + 4);
    float breg[8];
#pragma unroll
    for (int j = 0; j < 8; j++) breg[j] = bptr[(size_t)j * 768];

    const int lane = t & 63;
    const int w    = t >> 6;
    const int lr   = lane & 15;   // m (A) / n (B) within 16
    const int lq   = lane >> 4;   // k-quad

    floatx4 acc0 = {0,0,0,0}, acc1 = {0,0,0,0}, acc2 = {0,0,0,0}, acc3 = {0,0,0,0};

    for (int kt = 0; kt < 768; kt += 32) {
        __syncthreads();   // previous tile consumed
        short8 ap;
        ap[0]=f2bf(af0.x); ap[1]=f2bf(af0.y); ap[2]=f2bf(af0.z); ap[3]=f2bf(af0.w);
        ap[4]=f2bf(af1.x); ap[5]=f2bf(af1.y); ap[6]=f2bf(af1.z); ap[7]=f2bf(af1.w);
        *(short8*)&As[srow][skc] = ap;
        short8 bp;
        bp[0]=f2bf(breg[0]); bp[1]=f2bf(breg[1]); bp[2]=f2bf(breg[2]); bp[3]=f2bf(breg[3]);
        bp[4]=f2bf(breg[4]); bp[5]=f2bf(breg[5]); bp[6]=f2bf(breg[6]); bp[7]=f2bf(breg[7]);
        *(short8*)&Bs[ncolS][kg0] = bp;
        __syncthreads();

        if (kt + 32 < 768) {   // prefetch next tile (overlaps MFMA below)
            af0 = *(const float4*)(aptr + kt + 32);
            af1 = *(const float4*)(aptr + kt + 36);
#pragma unroll
            for (int j = 0; j < 8; j++) breg[j] = bptr[(size_t)(kt + 32 + j) * 768];
        }

        // fragments: A[m = lr][k = lq*8 + j], B[n = lr][k = lq*8 + j]
        short8 bfr = *(const short8*)&Bs[w * 16 + lr][lq * 8];
        short8 a0  = *(const short8*)&As[     lr][lq * 8];
        short8 a1  = *(const short8*)&As[16 + lr][lq * 8];
        short8 a2  = *(const short8*)&As[32 + lr][lq * 8];
        short8 a3  = *(const short8*)&As[48 + lr][lq * 8];
        acc0 = __builtin_amdgcn_mfma_f32_16x16x32_bf16(a0, bfr, acc0, 0, 0, 0);
        acc1 = __builtin_amdgcn_mfma_f32_16x16x32_bf16(a1, bfr, acc1, 0, 0, 0);
        acc2 = __builtin_amdgcn_mfma_f32_16x16x32_bf16(a2, bfr, acc2, 0, 0, 0);
        acc3 = __builtin_amdgcn_mfma_f32_16x16x32_bf16(a3, bfr, acc3, 0, 0, 0);
    }

    // C/D layout: col = lane&15 (n), row = (lane>>4)*4 + r (m)
    const int ncol = n0 + w * 16 + lr;
    const float bias = which ? 0.f : b1[ncol];
    ushort* __restrict__ dst = Hbf + (size_t)which * 393216 + ncol;
    const int rbase = m0 + lq * 4;
#pragma unroll
    for (int r = 0; r < 4; r++) {
        dst[(size_t)(rbase +      r) * 768] = (ushort)f2bf(acc0[r] + bias);
        dst[(size_t)(rbase + 16 + r) * 768] = (ushort)f2bf(acc1[r] + bias);
        dst[(size_t)(rbase + 32 + r) * 768] = (ushort)f2bf(acc2[r] + bias);
        dst[(size_t)(rbase + 48 + r) * 768] = (ushort)f2bf(acc3[r] + bias);
    }
}

// ---------------- K3: pair scoring ----------------
// grid (4, 4, 16): t0 = x*32, s0 = y*32, z = batch*4 + hchunk (192 h each)
__global__ __launch_bounds__(256) void pair_kernel(
    const ushort* __restrict__ Hbf, const float* __restrict__ W2,
    float* __restrict__ out)
{
    const int bb = blockIdx.z >> 2;
    const int hc = blockIdx.z & 3;
    const int s0 = blockIdx.y * 32;
    const int t0 = blockIdx.x * 32;
    const int tid = threadIdx.x;

    // stride 200 bf16 = 400 B (16B-aligned rows)
    __shared__ ushort hAs[32][200];
    __shared__ ushort hBs[32][200];
    __shared__ __align__(16) float w2s[384];

    const int hbase = hc * 192;
    const ushort* __restrict__ Asrc = Hbf +          (size_t)(bb * 128 + s0) * 768 + hbase;
    const ushort* __restrict__ Bsrc = Hbf + 393216 + (size_t)(bb * 128 + t0) * 768 + hbase;

    // stage 32 rows x 192 bf16 per array: 768 x 16B chunks, 3 per thread
#pragma unroll
    for (int i = 0; i < 3; i++) {
        const int c   = tid + i * 256;
        const int row = c / 24;
        const int c16 = c % 24;
        *(uint4*)&hAs[row][c16 * 8] = *(const uint4*)(Asrc + (size_t)row * 768 + c16 * 8);
        *(uint4*)&hBs[row][c16 * 8] = *(const uint4*)(Bsrc + (size_t)row * 768 + c16 * 8);
    }
    if (tid < 96) *(float4*)&w2s[tid * 4] = *(const float4*)&W2[hbase * 2 + tid * 4];
    __syncthreads();

    const int tl = tid & 15;   // t micro-pair: 2tl, 2tl+1
    const int sl = tid >> 4;   // s micro-pair: 2sl, 2sl+1

    float acc[2][2][2] = {};   // [si][tj][o]

    for (int h8 = 0; h8 < 192; h8 += 8) {
        const uint4 ra0 = *(const uint4*)&hAs[2 * sl    ][h8];
        const uint4 ra1 = *(const uint4*)&hAs[2 * sl + 1][h8];
        const uint4 rb0 = *(const uint4*)&hBs[2 * tl    ][h8];
        const uint4 rb1 = *(const uint4*)&hBs[2 * tl + 1][h8];
        const uint a0d[4] = {ra0.x, ra0.y, ra0.z, ra0.w};
        const uint a1d[4] = {ra1.x, ra1.y, ra1.z, ra1.w};
        const uint b0d[4] = {rb0.x, rb0.y, rb0.z, rb0.w};
        const uint b1d[4] = {rb1.x, rb1.y, rb1.z, rb1.w};
#pragma unroll
        for (int d = 0; d < 4; d++) {
            const float4 wv = *(const float4*)&w2s[h8 * 2 + d * 4];
            {   // low bf16 of each dword: h = h8 + 2d
                const float a0 = bflo(a0d[d]), a1 = bflo(a1d[d]);
                const float b0 = bflo(b0d[d]), b1 = bflo(b1d[d]);
                float h;
                h = fmaxf(a0 + b0, 0.f); acc[0][0][0] = fmaf(h, wv.x, acc[0][0][0]); acc[0][0][1] = fmaf(h, wv.y, acc[0][0][1]);
                h = fmaxf(a0 + b1, 0.f); acc[0][1][0] = fmaf(h, wv.x, acc[0][1][0]); acc[0][1][1] = fmaf(h, wv.y, acc[0][1][1]);
                h = fmaxf(a1 + b0, 0.f); acc[1][0][0] = fmaf(h, wv.x, acc[1][0][0]); acc[1][0][1] = fmaf(h, wv.y, acc[1][0][1]);
                h = fmaxf(a1 + b1, 0.f); acc[1][1][0] = fmaf(h, wv.x, acc[1][1][0]); acc[1][1][1] = fmaf(h, wv.y, acc[1][1][1]);
            }
            {   // high bf16: h = h8 + 2d + 1
                const float a0 = bfhi(a0d[d]), a1 = bfhi(a1d[d]);
                const float b0 = bfhi(b0d[d]), b1 = bfhi(b1d[d]);
                float h;
                h = fmaxf(a0 + b0, 0.f); acc[0][0][0] = fmaf(h, wv.z, acc[0][0][0]); acc[0][0][1] = fmaf(h, wv.w, acc[0][0][1]);
                h = fmaxf(a0 + b1, 0.f); acc[0][1][0] = fmaf(h, wv.z, acc[0][1][0]); acc[0][1][1] = fmaf(h, wv.w, acc[0][1][1]);
                h = fmaxf(a1 + b0, 0.f); acc[1][0][0] = fmaf(h, wv.z, acc[1][0][0]); acc[1][0][1] = fmaf(h, wv.w, acc[1][0][1]);
                h = fmaxf(a1 + b1, 0.f); acc[1][1][0] = fmaf(h, wv.z, acc[1][1][0]); acc[1][1][1] = fmaf(h, wv.w, acc[1][1][1]);
            }
        }
    }

    // out[b,s,t,o]: idx = (bb*128+s)*256 + t*2 + o
    const int sg = bb * 128 + s0 + 2 * sl;
    const int tg = t0 + 2 * tl;
    float* ob = out + (size_t)sg * 256 + tg * 2;
    atomicAdd(ob + 0,   acc[0][0][0]); atomicAdd(ob + 1,   acc[0][0][1]);
    atomicAdd(ob + 2,   acc[0][1][0]); atomicAdd(ob + 3,   acc[0][1][1]);
    atomicAdd(ob + 256, acc[1][0][0]); atomicAdd(ob + 257, acc[1][0][1]);
    atomicAdd(ob + 258, acc[1][1][0]); atomicAdd(ob + 259, acc[1][1][1]);
}

extern "C" void kernel_launch(void* const* d_in, const int* in_sizes, int n_in,
                              void* d_out, int out_size, void* d_ws, size_t ws_size,
                              hipStream_t stream) {
    const float* a  = (const float*)d_in[0];
    const float* b  = (const float*)d_in[1];
    const float* W1 = (const float*)d_in[2];
    const float* b1 = (const float*)d_in[3];
    const float* W2 = (const float*)d_in[4];
    const float* b2 = (const float*)d_in[5];
    float* out = (float*)d_out;

    ushort* Hbf = (ushort*)d_ws;   // [2][512][768] bf16 = 1.5 MB

    init_out_kernel<<<64, 256, 0, stream>>>(b2, out);
    gemm_kernel<<<dim3(12, 8, 2), 256, 0, stream>>>(a, b, W1, b1, Hbf);
    pair_kernel<<<dim3(4, 4, 16), 256, 0, stream>>>(Hbf, W2, out);
}

// Round 4
// 89.057 us; speedup vs baseline: 1.4895x; 1.1066x over previous
//
#include <hip/hip_runtime.h>
#include <hip/hip_fp16.h>

// RoleScorer, fused biaffine, fp16-h version:
//   hA = fp16(a @ W1[:768] + b1)   hB = fp16(b @ W1[768:])      (MFMA f16 GEMM)
//   out[b,s,t,:] = relu2(hA[s]+hB[t]) . W2pk + b2               (pk_f16 + fdot2)
//
// K1 gemm : MFMA 16x16x32_f16, 64x64 tile, 4 waves, K-step 32. A staged
//           f32->f16 (cvt_pkrtz), W1 transposed during staging. grid (12,8,2).
// K2 pair : 16x16 pair tile, full H=768 (no H-split -> no atomics, no init
//           kernel). h rows staged to LDS as fp16; W2 repacked per-block into
//           (o, h/2) fp16-pairs; inner loop = v_pk_add_f16 + v_pk_max_f16 +
//           2x v_dot2_f32_f16 per 2 h. grid (8,8,4) = 256 blocks = 1/CU.
//
// NOTE (profiling): __amd_rocclr_fillBufferAligned @ ~40.7us in the dispatch
// table is the harness re-poisoning the 268 MB d_ws each iteration; it is
// included in dur_us and is not addressable from kernel code. Fixed floor
// ~43us (poison + input restore).
//
// NOTE (types): __builtin_amdgcn_cvt_pkrtz returns a vector of __fp16, which
// clang will NOT implicitly convert to a _Float16 vector — bit-cast through
// memcpy (identical IEEE-half layout). mfma/fdot2 accept _Float16 vectors.

typedef __attribute__((ext_vector_type(2))) _Float16 half2t;
typedef __attribute__((ext_vector_type(8))) _Float16 half8t;
typedef __attribute__((ext_vector_type(4))) float floatx4;
typedef unsigned int uint;

__device__ __forceinline__ half2t pkrtz(float x, float y) {
    __fp16 r __attribute__((ext_vector_type(2))) = __builtin_amdgcn_cvt_pkrtz(x, y);
    half2t o; __builtin_memcpy(&o, &r, 4); return o;
}

// ---------------- K1: fp16 MFMA GEMM ----------------
// grid (12, 8, 2): n0 = x*64, m0 = y*64, which = z (0: a/W1-top/+b1, 1: b/W1-bot)
__global__ __launch_bounds__(256) void gemm_kernel(
    const float* __restrict__ a, const float* __restrict__ bmat,
    const float* __restrict__ W1, const float* __restrict__ b1,
    ushort* __restrict__ Hf)   // [2][512][768] fp16
{
    const int which = blockIdx.z;
    const int n0 = blockIdx.x * 64;
    const int m0 = blockIdx.y * 64;
    const int t  = threadIdx.x;

    // +8 pad: row stride 80 B (16B-multiple, keeps b128 alignment)
    __shared__ ushort As[64][40];   // [m][k]
    __shared__ ushort Bs[64][40];   // [n][k]

    const int srow = t >> 2;            // A: m row
    const int skc  = (t & 3) * 8;       // A: k chunk
    const float* __restrict__ Asrc = which ? bmat : a;
    const float* __restrict__ aptr = Asrc + (size_t)(m0 + srow) * 768 + skc;

    const int ncolS = t & 63;           // B: n col
    const int kg0   = (t >> 6) * 8;     // B: wave w owns k-rows 8w..8w+8
    const float* __restrict__ bptr = W1 + (size_t)(which * 768 + kg0) * 768 + n0 + ncolS;

    float4 af0 = *(const float4*)(aptr);
    float4 af1 = *(const float4*)(aptr + 4);
    float breg[8];
#pragma unroll
    for (int j = 0; j < 8; j++) breg[j] = bptr[(size_t)j * 768];

    const int lane = t & 63;
    const int w    = t >> 6;
    const int lr   = lane & 15;   // m (A) / n (B) within 16
    const int lq   = lane >> 4;   // k-quad

    floatx4 acc0 = {0,0,0,0}, acc1 = {0,0,0,0}, acc2 = {0,0,0,0}, acc3 = {0,0,0,0};

    for (int kt = 0; kt < 768; kt += 32) {
        __syncthreads();   // previous tile consumed
        half2t ap[4];
        ap[0] = pkrtz(af0.x, af0.y);
        ap[1] = pkrtz(af0.z, af0.w);
        ap[2] = pkrtz(af1.x, af1.y);
        ap[3] = pkrtz(af1.z, af1.w);
        __builtin_memcpy(&As[srow][skc], ap, 16);
        half2t bp[4];
        bp[0] = pkrtz(breg[0], breg[1]);
        bp[1] = pkrtz(breg[2], breg[3]);
        bp[2] = pkrtz(breg[4], breg[5]);
        bp[3] = pkrtz(breg[6], breg[7]);
        __builtin_memcpy(&Bs[ncolS][kg0], bp, 16);
        __syncthreads();

        if (kt + 32 < 768) {   // prefetch next tile (overlaps MFMA)
            af0 = *(const float4*)(aptr + kt + 32);
            af1 = *(const float4*)(aptr + kt + 36);
#pragma unroll
            for (int j = 0; j < 8; j++) breg[j] = bptr[(size_t)(kt + 32 + j) * 768];
        }

        half8t bfr, a0, a1, a2, a3;
        __builtin_memcpy(&bfr, &Bs[w * 16 + lr][lq * 8], 16);
        __builtin_memcpy(&a0,  &As[     lr][lq * 8], 16);
        __builtin_memcpy(&a1,  &As[16 + lr][lq * 8], 16);
        __builtin_memcpy(&a2,  &As[32 + lr][lq * 8], 16);
        __builtin_memcpy(&a3,  &As[48 + lr][lq * 8], 16);
        acc0 = __builtin_amdgcn_mfma_f32_16x16x32_f16(a0, bfr, acc0, 0, 0, 0);
        acc1 = __builtin_amdgcn_mfma_f32_16x16x32_f16(a1, bfr, acc1, 0, 0, 0);
        acc2 = __builtin_amdgcn_mfma_f32_16x16x32_f16(a2, bfr, acc2, 0, 0, 0);
        acc3 = __builtin_amdgcn_mfma_f32_16x16x32_f16(a3, bfr, acc3, 0, 0, 0);
    }

    // C/D layout: col = lane&15 (n), row = (lane>>4)*4 + r (m)
    const int ncol = n0 + w * 16 + lr;
    const float bias = which ? 0.f : b1[ncol];
    ushort* __restrict__ dst = Hf + (size_t)which * 393216 + ncol;
    const int rbase = m0 + lq * 4;
#pragma unroll
    for (int r = 0; r < 4; r++) {
        _Float16 v0 = (_Float16)(acc0[r] + bias);
        _Float16 v1 = (_Float16)(acc1[r] + bias);
        _Float16 v2 = (_Float16)(acc2[r] + bias);
        _Float16 v3 = (_Float16)(acc3[r] + bias);
        ushort u0, u1, u2, u3;
        __builtin_memcpy(&u0, &v0, 2); __builtin_memcpy(&u1, &v1, 2);
        __builtin_memcpy(&u2, &v2, 2); __builtin_memcpy(&u3, &v3, 2);
        dst[(size_t)(rbase +      r) * 768] = u0;
        dst[(size_t)(rbase + 16 + r) * 768] = u1;
        dst[(size_t)(rbase + 32 + r) * 768] = u2;
        dst[(size_t)(rbase + 48 + r) * 768] = u3;
    }
}

// ---------------- K2: pair scoring, full-H, no atomics ----------------
// grid (8, 8, 4): t0 = x*16, s0 = y*16, bb = z
__global__ __launch_bounds__(256) void pair_kernel(
    const ushort* __restrict__ Hf, const float* __restrict__ W2,
    const float* __restrict__ b2, float* __restrict__ out)
{
    const int bb = blockIdx.z;
    const int s0 = blockIdx.y * 16;
    const int t0 = blockIdx.x * 16;
    const int tid = threadIdx.x;

    // +8 pad: row stride 1552 B (16B-multiple); rows shift 4 banks -> 2-way max
    __shared__ ushort hAs[16][776];
    __shared__ ushort hBs[16][776];
    __shared__ uint w2s[768];   // [o][h/2] fp16-pairs

    const ushort* __restrict__ Asrc = Hf +          (size_t)(bb * 128 + s0) * 768;
    const ushort* __restrict__ Bsrc = Hf + 393216 + (size_t)(bb * 128 + t0) * 768;

    // stage 16 rows x 768 fp16 per array: 1536 x 16B chunks, 6 per thread
#pragma unroll
    for (int i = 0; i < 6; i++) {
        const int c   = tid + i * 256;
        const int row = c / 96;
        const int col = (c % 96) * 8;
        *(uint4*)&hAs[row][col] = *(const uint4*)(Asrc + (size_t)row * 768 + col);
        *(uint4*)&hBs[row][col] = *(const uint4*)(Bsrc + (size_t)row * 768 + col);
    }
    // repack W2 (768,2) f32 -> w2s[o*384 + h2] = pk(W2[2h2][o], W2[2h2+1][o])
#pragma unroll
    for (int j = tid; j < 768; j += 256) {
        const int o  = (j >= 384) ? 1 : 0;
        const int h2 = j - o * 384;
        half2t p = pkrtz(W2[4 * h2 + o], W2[4 * h2 + 2 + o]);
        uint u; __builtin_memcpy(&u, &p, 4);
        w2s[j] = u;
    }
    __syncthreads();

    const int sl = tid >> 4;
    const int tl = tid & 15;
    const ushort* __restrict__ arow = &hAs[sl][0];
    const ushort* __restrict__ brow = &hBs[tl][0];

    float acc0 = 0.f, acc1 = 0.f;
    const half2t zero = {(_Float16)0.f, (_Float16)0.f};

#pragma unroll 8
    for (int h8 = 0; h8 < 768; h8 += 8) {
        half2t pa[4], pb[4], w0[4], w1[4];
        __builtin_memcpy(pa, arow + h8, 16);
        __builtin_memcpy(pb, brow + h8, 16);
        __builtin_memcpy(w0, &w2s[h8 / 2], 16);
        __builtin_memcpy(w1, &w2s[384 + h8 / 2], 16);
#pragma unroll
        for (int j = 0; j < 4; j++) {
            half2t s = pa[j] + pb[j];                       // v_pk_add_f16
            s = __builtin_elementwise_max(s, zero);         // v_pk_max_f16
            acc0 = __builtin_amdgcn_fdot2(s, w0[j], acc0, false);  // v_dot2_f32_f16
            acc1 = __builtin_amdgcn_fdot2(s, w1[j], acc1, false);
        }
    }

    // out[b,s,t,o], coalesced float2 per thread
    const int sg = bb * 128 + s0 + sl;
    const int tg = t0 + tl;
    float2 r = make_float2(acc0 + b2[0], acc1 + b2[1]);
    *(float2*)&out[((size_t)sg * 128 + tg) * 2] = r;
}

extern "C" void kernel_launch(void* const* d_in, const int* in_sizes, int n_in,
                              void* d_out, int out_size, void* d_ws, size_t ws_size,
                              hipStream_t stream) {
    const float* a  = (const float*)d_in[0];
    const float* b  = (const float*)d_in[1];
    const float* W1 = (const float*)d_in[2];
    const float* b1 = (const float*)d_in[3];
    const float* W2 = (const float*)d_in[4];
    const float* b2 = (const float*)d_in[5];
    float* out = (float*)d_out;

    ushort* Hf = (ushort*)d_ws;   // [2][512][768] fp16 = 1.5 MB

    gemm_kernel<<<dim3(12, 8, 2), 256, 0, stream>>>(a, b, W1, b1, Hf);
    pair_kernel<<<dim3(8, 8, 4), 256, 0, stream>>>(Hf, W2, b2, out);
}

// Round 5
// 88.987 us; speedup vs baseline: 1.4907x; 1.0008x over previous
//
#include <hip/hip_runtime.h>
#include <hip/hip_fp16.h>

// RoleScorer, fused biaffine, fp16-h:
//   hA = fp16(a @ W1[:768] + b1)   hB = fp16(b @ W1[768:])      (MFMA f16 GEMM)
//   out[b,s,t,:] = relu2(hA[s]+hB[t]) . W2pk + b2               (pk_f16 + fdot2)
//
// K1 gemm : MFMA 16x16x32_f16, 64x64 tile, BK=64 (12 K-iters), DOUBLE-BUFFERED
//           LDS with ONE barrier per iter (R4 post-mortem: 2-barrier BK=32 was
//           ~1us/iter barrier-convoy-bound at 1 wave/SIMD; R1 BK=16 = 48 iters
//           = 50us confirms per-iter-constant cost). grid (12,8,2).
// K2 pair : 16x16 pair tile, full H=768, no atomics. UNCHANGED from R4 (clean
//           delta isolates gemm; if dur stays ~85+, pair is the bottleneck).
//
// NOTE (profiling): __amd_rocclr_fillBufferAligned ~41us = harness re-poison
// of 268 MB d_ws, counted inside dur_us; fixed ~43us floor incl. restores.
// NOTE (types): cvt_pkrtz returns __fp16 vector; bit-cast to _Float16 vector.

typedef __attribute__((ext_vector_type(2))) _Float16 half2t;
typedef __attribute__((ext_vector_type(8))) _Float16 half8t;
typedef __attribute__((ext_vector_type(4))) float floatx4;
typedef unsigned int uint;

__device__ __forceinline__ half2t pkrtz(float x, float y) {
    __fp16 r __attribute__((ext_vector_type(2))) = __builtin_amdgcn_cvt_pkrtz(x, y);
    half2t o; __builtin_memcpy(&o, &r, 4); return o;
}

// ---------------- K1: fp16 MFMA GEMM, BK=64, 1-barrier dbuf ----------------
// grid (12, 8, 2): n0 = x*64, m0 = y*64, which = z (0: a/W1-top/+b1, 1: b/W1-bot)
__global__ __launch_bounds__(256) void gemm_kernel(
    const float* __restrict__ a, const float* __restrict__ bmat,
    const float* __restrict__ W1, const float* __restrict__ b1,
    ushort* __restrict__ Hf)   // [2][512][768] fp16
{
    const int which = blockIdx.z;
    const int n0 = blockIdx.x * 64;
    const int m0 = blockIdx.y * 64;
    const int t  = threadIdx.x;

    // row stride 72 shorts = 144 B (16B-multiple for b128). Write conflicts:
    // As 2-way (free); Bs b128 8-way (~35cyc x2/iter, acceptable — any 16B-
    // aligned stride collides for 64-consecutive-row writes).
    __shared__ ushort As[2][64][72];   // [buf][m][k]
    __shared__ ushort Bs[2][64][72];   // [buf][n][k]

    // A staging: row = t>>2, kc = (t&3)*16 (16 f32 = 4 float4 per iter)
    const int arow = t >> 2;
    const int akc  = (t & 3) * 16;
    const float* __restrict__ Asrc = which ? bmat : a;
    const float* __restrict__ aptr = Asrc + (size_t)(m0 + arow) * 768 + akc;

    // B staging: ncol = t&63, wave w owns k-rows w*16..w*16+15 (16 scalar/iter)
    const int ncol = t & 63;
    const int kg   = (t >> 6) * 16;
    const float* __restrict__ bptr = W1 + (size_t)(which * 768 + kg) * 768 + n0 + ncol;

    const int lane = t & 63;
    const int w    = t >> 6;
    const int lr   = lane & 15;   // m (A) / n (B) within 16
    const int lq   = lane >> 4;   // k-quad

    floatx4 acc0 = {0,0,0,0}, acc1 = {0,0,0,0}, acc2 = {0,0,0,0}, acc3 = {0,0,0,0};

    // preload tile 0
    float4 a4[4];
    float  br[16];
#pragma unroll
    for (int i = 0; i < 4; i++) a4[i] = *(const float4*)(aptr + 4 * i);
#pragma unroll
    for (int j = 0; j < 16; j++) br[j] = bptr[(size_t)j * 768];

    int p = 0;
    for (int kt = 0; kt < 768; kt += 64, p ^= 1) {
        // pack current tile -> LDS buf p
        half2t ap[8];
#pragma unroll
        for (int i = 0; i < 4; i++) {
            ap[2 * i    ] = pkrtz(a4[i].x, a4[i].y);
            ap[2 * i + 1] = pkrtz(a4[i].z, a4[i].w);
        }
        __builtin_memcpy(&As[p][arow][akc],     &ap[0], 16);
        __builtin_memcpy(&As[p][arow][akc + 8], &ap[4], 16);
        half2t bp[8];
#pragma unroll
        for (int j = 0; j < 8; j++) bp[j] = pkrtz(br[2 * j], br[2 * j + 1]);
        __builtin_memcpy(&Bs[p][ncol][kg],     &bp[0], 16);
        __builtin_memcpy(&Bs[p][ncol][kg + 8], &bp[4], 16);

        __syncthreads();   // the ONLY barrier per iter (lgkmcnt(0) at barrier
                           // makes prior-iter reads of buf p^1 safely drained)

        if (kt + 64 < 768) {   // prefetch next tile (overlaps MFMA below)
#pragma unroll
            for (int i = 0; i < 4; i++)
                a4[i] = *(const float4*)(aptr + kt + 64 + 4 * i);
#pragma unroll
            for (int j = 0; j < 16; j++)
                br[j] = bptr[(size_t)(kt + 64 + j) * 768];
        }

#pragma unroll
        for (int h = 0; h < 2; h++) {
            const int kb = h * 32 + lq * 8;
            half8t bfr, f0, f1, f2, f3;
            __builtin_memcpy(&bfr, &Bs[p][w * 16 + lr][kb], 16);
            __builtin_memcpy(&f0,  &As[p][     lr][kb], 16);
            __builtin_memcpy(&f1,  &As[p][16 + lr][kb], 16);
            __builtin_memcpy(&f2,  &As[p][32 + lr][kb], 16);
            __builtin_memcpy(&f3,  &As[p][48 + lr][kb], 16);
            acc0 = __builtin_amdgcn_mfma_f32_16x16x32_f16(f0, bfr, acc0, 0, 0, 0);
            acc1 = __builtin_amdgcn_mfma_f32_16x16x32_f16(f1, bfr, acc1, 0, 0, 0);
            acc2 = __builtin_amdgcn_mfma_f32_16x16x32_f16(f2, bfr, acc2, 0, 0, 0);
            acc3 = __builtin_amdgcn_mfma_f32_16x16x32_f16(f3, bfr, acc3, 0, 0, 0);
        }
    }

    // C/D layout: col = lane&15 (n), row = (lane>>4)*4 + r (m)
    const int ncolO = n0 + w * 16 + lr;
    const float bias = which ? 0.f : b1[ncolO];
    ushort* __restrict__ dst = Hf + (size_t)which * 393216 + ncolO;
    const int rbase = m0 + lq * 4;
#pragma unroll
    for (int r = 0; r < 4; r++) {
        _Float16 v0 = (_Float16)(acc0[r] + bias);
        _Float16 v1 = (_Float16)(acc1[r] + bias);
        _Float16 v2 = (_Float16)(acc2[r] + bias);
        _Float16 v3 = (_Float16)(acc3[r] + bias);
        ushort u0, u1, u2, u3;
        __builtin_memcpy(&u0, &v0, 2); __builtin_memcpy(&u1, &v1, 2);
        __builtin_memcpy(&u2, &v2, 2); __builtin_memcpy(&u3, &v3, 2);
        dst[(size_t)(rbase +      r) * 768] = u0;
        dst[(size_t)(rbase + 16 + r) * 768] = u1;
        dst[(size_t)(rbase + 32 + r) * 768] = u2;
        dst[(size_t)(rbase + 48 + r) * 768] = u3;
    }
}

// ---------------- K2: pair scoring, full-H, no atomics (UNCHANGED) ----------
// grid (8, 8, 4): t0 = x*16, s0 = y*16, bb = z
__global__ __launch_bounds__(256) void pair_kernel(
    const ushort* __restrict__ Hf, const float* __restrict__ W2,
    const float* __restrict__ b2, float* __restrict__ out)
{
    const int bb = blockIdx.z;
    const int s0 = blockIdx.y * 16;
    const int t0 = blockIdx.x * 16;
    const int tid = threadIdx.x;

    __shared__ ushort hAs[16][776];
    __shared__ ushort hBs[16][776];
    __shared__ uint w2s[768];   // [o][h/2] fp16-pairs

    const ushort* __restrict__ Asrc = Hf +          (size_t)(bb * 128 + s0) * 768;
    const ushort* __restrict__ Bsrc = Hf + 393216 + (size_t)(bb * 128 + t0) * 768;

#pragma unroll
    for (int i = 0; i < 6; i++) {
        const int c   = tid + i * 256;
        const int row = c / 96;
        const int col = (c % 96) * 8;
        *(uint4*)&hAs[row][col] = *(const uint4*)(Asrc + (size_t)row * 768 + col);
        *(uint4*)&hBs[row][col] = *(const uint4*)(Bsrc + (size_t)row * 768 + col);
    }
#pragma unroll
    for (int j = tid; j < 768; j += 256) {
        const int o  = (j >= 384) ? 1 : 0;
        const int h2 = j - o * 384;
        half2t p = pkrtz(W2[4 * h2 + o], W2[4 * h2 + 2 + o]);
        uint u; __builtin_memcpy(&u, &p, 4);
        w2s[j] = u;
    }
    __syncthreads();

    const int sl = tid >> 4;
    const int tl = tid & 15;
    const ushort* __restrict__ arow = &hAs[sl][0];
    const ushort* __restrict__ brow = &hBs[tl][0];

    float acc0 = 0.f, acc1 = 0.f;
    const half2t zero = {(_Float16)0.f, (_Float16)0.f};

#pragma unroll 8
    for (int h8 = 0; h8 < 768; h8 += 8) {
        half2t pa[4], pb[4], w0[4], w1[4];
        __builtin_memcpy(pa, arow + h8, 16);
        __builtin_memcpy(pb, brow + h8, 16);
        __builtin_memcpy(w0, &w2s[h8 / 2], 16);
        __builtin_memcpy(w1, &w2s[384 + h8 / 2], 16);
#pragma unroll
        for (int j = 0; j < 4; j++) {
            half2t s = pa[j] + pb[j];                       // v_pk_add_f16
            s = __builtin_elementwise_max(s, zero);         // v_pk_max_f16
            acc0 = __builtin_amdgcn_fdot2(s, w0[j], acc0, false);  // v_dot2_f32_f16
            acc1 = __builtin_amdgcn_fdot2(s, w1[j], acc1, false);
        }
    }

    const int sg = bb * 128 + s0 + sl;
    const int tg = t0 + tl;
    float2 r = make_float2(acc0 + b2[0], acc1 + b2[1]);
    *(float2*)&out[((size_t)sg * 128 + tg) * 2] = r;
}

extern "C" void kernel_launch(void* const* d_in, const int* in_sizes, int n_in,
                              void* d_out, int out_size, void* d_ws, size_t ws_size,
                              hipStream_t stream) {
    const float* a  = (const float*)d_in[0];
    const float* b  = (const float*)d_in[1];
    const float* W1 = (const float*)d_in[2];
    const float* b1 = (const float*)d_in[3];
    const float* W2 = (const float*)d_in[4];
    const float* b2 = (const float*)d_in[5];
    float* out = (float*)d_out;

    ushort* Hf = (ushort*)d_ws;   // [2][512][768] fp16 = 1.5 MB

    gemm_kernel<<<dim3(12, 8, 2), 256, 0, stream>>>(a, b, W1, b1, Hf);
    pair_kernel<<<dim3(8, 8, 4), 256, 0, stream>>>(Hf, W2, b2, out);
}